// Round 6
// baseline (47.644 us; speedup 1.0000x reference)
//
#include <hip/hip_runtime.h>

// Separable 3x3 window: w = outer(v,v), v = [A_W, B_W, A_W]
#define A_W 0.30780133f
#define B_W 0.38439735f

#define CROP_LO 5
#define CROP_HI 507
#define BT 256

// LDS tile per block: 2 images x 34 rows x 34 float4 (136 floats = 544B/row).
// Output tile: 128 cols x 32 rows.
#define LROWF4 34
#define LROWF  136
#define IMGF4  1156          // 34*34 float4 per image
#define IMGF   4624          // floats per image plane

struct H10 { float s1[2], s2[2], s11[2], s22[2], s12[2]; };

__device__ __forceinline__ void hsum2(const float x[4], const float y[4], H10& h) {
#pragma unroll
    for (int k = 0; k < 2; ++k) {
        float xl = x[k], xc = x[k + 1], xr = x[k + 2];
        float yl = y[k], yc = y[k + 1], yr = y[k + 2];
        h.s1[k]  = A_W * (xl + xr)           + B_W * xc;
        h.s2[k]  = A_W * (yl + yr)           + B_W * yc;
        h.s11[k] = A_W * (xl * xl + xr * xr) + B_W * (xc * xc);
        h.s22[k] = A_W * (yl * yl + yr * yr) + B_W * (yc * yc);
        h.s12[k] = A_W * (xl * yl + xr * yr) + B_W * (xc * yc);
    }
}

__global__ __launch_bounds__(BT, 4) void ssim_loss_main(
    const float* __restrict__ X, const float* __restrict__ Y,
    float* __restrict__ partials) {
    __shared__ float4 tile4[2 * IMGF4];   // 36992 B

    const int t  = threadIdx.x;
    const int bx = blockIdx.x;            // 0..3  (128-col tiles)
    const int sy = blockIdx.y;            // 0..15 (32-row strips)
    const int b  = blockIdx.z;
    const int c0 = 128 * bx;
    const int i0 = CROP_LO + 32 * sy;     // 5..485

    const float4* X4 = (const float4*)X;
    const float4* Y4 = (const float4*)Y;
    const int ib = b * 65536;             // float4 per 512x512 image

    // ---- Stage: bulk independent float4 loads, each byte fetched once ----
#pragma unroll
    for (int img = 0; img < 2; ++img) {
        const float4* src = img ? Y4 : X4;
#pragma unroll
        for (int k = 0; k < 5; ++k) {
            int f = t + BT * k;
            if (f < IMGF4) {
                int row = f / LROWF4;                       // 0..33
                int c4  = f - row * LROWF4;                 // 0..33
                int gr  = min(i0 - 1 + row, 511);           // clamp bottom
                int g4  = min(max(32 * bx - 1 + c4, 0), 127); // clamp l/r
                tile4[img * IMGF4 + f] = src[ib + gr * 128 + g4];
            }
        }
    }
    __syncthreads();

    // ---- Compute: thread owns 2 cols x 8 rows; sliding 3-row h-sum window ----
    const float* L = (const float*)tile4;
    const int cg  = t & 63;               // col pair 0..63 -> cols c0+2cg{,+1}
    const int rs  = t >> 6;               // row slice 0..3 -> rows i0+8rs..+7
    const int lr0 = 8 * rs;
    const int or0 = i0 + 8 * rs;
    const int lcol = 2 * cg + 3;          // leftmost window float in LDS row

    float cm0, cm1;
    {
        int gc0 = c0 + 2 * cg, gc1 = gc0 + 1;
        cm0 = (gc0 >= CROP_LO && gc0 < CROP_HI) ? 1.0f : 0.0f;
        cm1 = (gc1 >= CROP_LO && gc1 < CROP_HI) ? 1.0f : 0.0f;
    }

    auto ldrow = [&](int img, int lr, float v[4]) {
        const float* P = L + img * IMGF + lr * LROWF + lcol;
        v[0] = P[0];                       // lane-consecutive: 2-way alias, free
        float2 m = *(const float2*)(P + 1);// 8B-aligned (lcol+1 even)
        v[1] = m.x; v[2] = m.y;
        v[3] = P[3];
    };

    H10 Ph, Ch, Nh;
    float x[4], y[4];
    ldrow(0, lr0, x);     ldrow(1, lr0, y);     hsum2(x, y, Ph);
    ldrow(0, lr0 + 1, x); ldrow(1, lr0 + 1, y); hsum2(x, y, Ch);

    float acc = 0.0f;
#pragma unroll
    for (int rr = 0; rr < 8; ++rr) {
        ldrow(0, lr0 + 2 + rr, x); ldrow(1, lr0 + 2 + rr, y); hsum2(x, y, Nh);
        float racc = 0.0f;
#pragma unroll
        for (int k = 0; k < 2; ++k) {
            float s1  = A_W * (Ph.s1[k]  + Nh.s1[k])  + B_W * Ch.s1[k];
            float s2  = A_W * (Ph.s2[k]  + Nh.s2[k])  + B_W * Ch.s2[k];
            float s11 = A_W * (Ph.s11[k] + Nh.s11[k]) + B_W * Ch.s11[k];
            float s22 = A_W * (Ph.s22[k] + Nh.s22[k]) + B_W * Ch.s22[k];
            float s12 = A_W * (Ph.s12[k] + Nh.s12[k]) + B_W * Ch.s12[k];
            float v1 = s11 - s1 * s1;      // sigma1_sq
            float v2 = s22 - s2 * s2;      // sigma2_sq
            float cv = s12 - s1 * s2;      // sigma12
            racc += (k ? cm1 : cm0) * (v1 * v2 - 2.0f * cv);
        }
        acc += (or0 + rr < CROP_HI) ? racc : 0.0f;
        Ph = Ch; Ch = Nh;
    }

    // ---- Block reduction (4 waves) ----
    for (int off = 32; off > 0; off >>= 1) acc += __shfl_down(acc, off, 64);
    __shared__ float wsum[BT / 64];
    if ((t & 63) == 0) wsum[t >> 6] = acc;
    __syncthreads();
    if (t == 0)
        partials[bx + 4 * (sy + 16 * b)] = wsum[0] + wsum[1] + wsum[2] + wsum[3];
}

__global__ __launch_bounds__(256) void ssim_loss_finalize(
    const float* __restrict__ partials, int n, float* __restrict__ out) {
    const int tid = threadIdx.x;
    float s = 0.0f;
    for (int i = tid; i < n; i += 256) s += partials[i];
    for (int off = 32; off > 0; off >>= 1) s += __shfl_down(s, off, 64);
    __shared__ float wsum[4];
    if ((tid & 63) == 0) wsum[tid >> 6] = s;
    __syncthreads();
    if (tid == 0) {
        float total = wsum[0] + wsum[1] + wsum[2] + wsum[3];
        out[0] = total * (1.0f / 252004.0f);  // mean over 502*502, summed over batch
    }
}

extern "C" void kernel_launch(void* const* d_in, const int* in_sizes, int n_in,
                              void* d_out, int out_size, void* d_ws, size_t ws_size,
                              hipStream_t stream) {
    const float* X = (const float*)d_in[0];
    const float* Y = (const float*)d_in[1];
    float* out = (float*)d_out;
    float* partials = (float*)d_ws;       // 4*16*64 = 4096 floats

    dim3 grid(4, 16, 64);
    ssim_loss_main<<<grid, BT, 0, stream>>>(X, Y, partials);
    ssim_loss_finalize<<<1, 256, 0, stream>>>(partials, 4096, out);
}

// Round 7
// 43.510 us; speedup vs baseline: 1.0950x; 1.0950x over previous
//
#include <hip/hip_runtime.h>

// Separable 3x3 window: w = outer(v,v), v = [A_W, B_W, A_W]
#define A_W 0.30780133f
#define B_W 0.38439735f

#define IMG_W 512
#define CROP_LO 5
#define CROP_HI 507          // exclusive; rows/cols 5..506 kept (502 each)
#define STRIP 16
#define NSTRIPS 32
#define BT 256

// Per-row horizontal sums for 2 owned columns.
struct H10 { float a1[2], a2[2], a11[2], a22[2], a12[2]; };

__global__ __launch_bounds__(BT) void ssim_loss_main(
    const float* __restrict__ X, const float* __restrict__ Y,
    float* __restrict__ partials) {
    const int t  = threadIdx.x;
    const int l  = t & 63;                 // lane
    const int w  = t >> 6;                 // wave 0..3
    const int c0 = 128 * w + 2 * l;        // owned cols c0, c0+1 (c0 even)
    const int b  = blockIdx.y;
    const int i0 = CROP_LO + STRIP * blockIdx.x;   // 5..501

    const float* Xb = X + (size_t)b * IMG_W * IMG_W;
    const float* Yb = Y + (size_t)b * IMG_W * IMG_W;

    const float cm0 = (c0     >= CROP_LO && c0     < CROP_HI) ? 1.0f : 0.0f;
    const float cm1 = (c0 + 1 >= CROP_LO && c0 + 1 < CROP_HI) ? 1.0f : 0.0f;
    const int clh = max(c0 - 1, 0);        // left-halo col (lane 0 only)
    const int crh = min(c0 + 2, IMG_W - 1);// right-halo col (lane 63 only)

    // Load one row (both images), distribute halos via wave shuffle,
    // produce the 10 horizontal sums.
    auto hrow = [&](int row, H10& h) {
        const float* Xr = Xb + (size_t)row * IMG_W;
        const float* Yr = Yb + (size_t)row * IMG_W;
        float2 x = *(const float2*)(Xr + c0);
        float2 y = *(const float2*)(Yr + c0);
        float xl = __shfl_up(x.y, 1, 64);
        float yl = __shfl_up(y.y, 1, 64);
        float xr = __shfl_down(x.x, 1, 64);
        float yr = __shfl_down(y.x, 1, 64);
        if (l == 0)  { xl = Xr[clh]; yl = Yr[clh]; }
        if (l == 63) { xr = Xr[crh]; yr = Yr[crh]; }
        // col c0:   window (xl, x.x, x.y) ; col c0+1: window (x.x, x.y, xr)
        h.a1[0]  = A_W * (xl + x.y)             + B_W * x.x;
        h.a1[1]  = A_W * (x.x + xr)             + B_W * x.y;
        h.a2[0]  = A_W * (yl + y.y)             + B_W * y.x;
        h.a2[1]  = A_W * (y.x + yr)             + B_W * y.y;
        h.a11[0] = A_W * (xl * xl + x.y * x.y)  + B_W * (x.x * x.x);
        h.a11[1] = A_W * (x.x * x.x + xr * xr)  + B_W * (x.y * x.y);
        h.a22[0] = A_W * (yl * yl + y.y * y.y)  + B_W * (y.x * y.x);
        h.a22[1] = A_W * (y.x * y.x + yr * yr)  + B_W * (y.y * y.y);
        h.a12[0] = A_W * (xl * yl + x.y * y.y)  + B_W * (x.x * y.x);
        h.a12[1] = A_W * (x.x * y.x + xr * yr)  + B_W * (x.y * y.y);
    };

    H10 P, C, N;
    hrow(i0 - 1, P);
    hrow(i0,     C);

    float acc = 0.0f;
#pragma unroll
    for (int rr = 0; rr < STRIP; ++rr) {
        hrow(min(i0 + rr + 1, IMG_W - 1), N);

        float racc = 0.0f;
#pragma unroll
        for (int k = 0; k < 2; ++k) {
            float s1  = A_W * (P.a1[k]  + N.a1[k])  + B_W * C.a1[k];
            float s2  = A_W * (P.a2[k]  + N.a2[k])  + B_W * C.a2[k];
            float s11 = A_W * (P.a11[k] + N.a11[k]) + B_W * C.a11[k];
            float s22 = A_W * (P.a22[k] + N.a22[k]) + B_W * C.a22[k];
            float s12 = A_W * (P.a12[k] + N.a12[k]) + B_W * C.a12[k];
            float v1 = s11 - s1 * s1;      // sigma1_sq
            float v2 = s22 - s2 * s2;      // sigma2_sq
            float cv = s12 - s1 * s2;      // sigma12
            racc += (k ? cm1 : cm0) * (v1 * v2 - 2.0f * cv);
        }
        acc += (i0 + rr < CROP_HI) ? racc : 0.0f;   // row mask (tail strip)
        P = C; C = N;
    }

    // Block reduction: 4 waves.
    for (int off = 32; off > 0; off >>= 1) acc += __shfl_down(acc, off, 64);
    __shared__ float wsum[BT / 64];
    if (l == 0) wsum[w] = acc;
    __syncthreads();
    if (t == 0)
        partials[blockIdx.x + NSTRIPS * b] = wsum[0] + wsum[1] + wsum[2] + wsum[3];
}

__global__ __launch_bounds__(256) void ssim_loss_finalize(
    const float* __restrict__ partials, int n, float* __restrict__ out) {
    const int tid = threadIdx.x;
    float s = 0.0f;
    for (int i = tid; i < n; i += 256) s += partials[i];
    for (int off = 32; off > 0; off >>= 1) s += __shfl_down(s, off, 64);
    __shared__ float wsum[4];
    if ((tid & 63) == 0) wsum[tid >> 6] = s;
    __syncthreads();
    if (tid == 0) {
        float total = wsum[0] + wsum[1] + wsum[2] + wsum[3];
        out[0] = total * (1.0f / 252004.0f);   // mean over 502*502, summed over batch
    }
}

extern "C" void kernel_launch(void* const* d_in, const int* in_sizes, int n_in,
                              void* d_out, int out_size, void* d_ws, size_t ws_size,
                              hipStream_t stream) {
    const float* X = (const float*)d_in[0];
    const float* Y = (const float*)d_in[1];
    float* out = (float*)d_out;
    float* partials = (float*)d_ws;   // NSTRIPS*64 = 2048 floats

    dim3 grid(NSTRIPS, 64);
    ssim_loss_main<<<grid, BT, 0, stream>>>(X, Y, partials);
    ssim_loss_finalize<<<1, 256, 0, stream>>>(partials, NSTRIPS * 64, out);
}

// Round 8
// 31.191 us; speedup vs baseline: 1.5275x; 1.3950x over previous
//
#include <hip/hip_runtime.h>

// Separable 3x3 window: w = outer(v,v), v = [A_W, B_W, A_W]
#define A_W 0.30780133f
#define B_W 0.38439735f

#define IMG_W 512
#define CROP_LO 5
#define CROP_HI 507          // exclusive; rows/cols 5..506 kept (502 each)
#define STRIP 16
#define NSTRIPS 32
#define BT 256

// Per-row horizontal sums for the thread's 2 owned columns.
struct H10 { float a1[2], a2[2], a11[2], a22[2], a12[2]; };

__global__ __launch_bounds__(BT) void ssim_loss_main(
    const float* __restrict__ X, const float* __restrict__ Y,
    float* __restrict__ partials) {
    const int t  = threadIdx.x;
    const int c0 = 4 + 2 * t;              // owned cols c0, c0+1 (c0 even)
    const int lc = min(c0, 508) - 1;       // float4 window base: [lc .. lc+3]
    const int b  = blockIdx.y;
    const int i0 = CROP_LO + STRIP * blockIdx.x;   // 5..501

    const float* Xb = X + (size_t)b * IMG_W * IMG_W;
    const float* Yb = Y + (size_t)b * IMG_W * IMG_W;

    const float cm0 = (c0     >= CROP_LO && c0     < CROP_HI) ? 1.0f : 0.0f;
    const float cm1 = (c0 + 1 >= CROP_LO && c0 + 1 < CROP_HI) ? 1.0f : 0.0f;

    // One float4 per image per row: covers cols [c0-1 .. c0+2], the union of
    // both owned columns' 3-wide windows. No shuffles, no halo branches.
    auto hrow = [&](int row, H10& h) {
        const float4 x = *(const float4*)(Xb + (size_t)row * IMG_W + lc);
        const float4 y = *(const float4*)(Yb + (size_t)row * IMG_W + lc);
        // squares / cross products (shared between the two columns)
        float xx0 = x.x * x.x, xx1 = x.y * x.y, xx2 = x.z * x.z, xx3 = x.w * x.w;
        float yy0 = y.x * y.x, yy1 = y.y * y.y, yy2 = y.z * y.z, yy3 = y.w * y.w;
        float xy0 = x.x * y.x, xy1 = x.y * y.y, xy2 = x.z * y.z, xy3 = x.w * y.w;
        h.a1[0]  = A_W * (x.x + x.z) + B_W * x.y;
        h.a1[1]  = A_W * (x.y + x.w) + B_W * x.z;
        h.a2[0]  = A_W * (y.x + y.z) + B_W * y.y;
        h.a2[1]  = A_W * (y.y + y.w) + B_W * y.z;
        h.a11[0] = A_W * (xx0 + xx2) + B_W * xx1;
        h.a11[1] = A_W * (xx1 + xx3) + B_W * xx2;
        h.a22[0] = A_W * (yy0 + yy2) + B_W * yy1;
        h.a22[1] = A_W * (yy1 + yy3) + B_W * yy2;
        h.a12[0] = A_W * (xy0 + xy2) + B_W * xy1;
        h.a12[1] = A_W * (xy1 + xy3) + B_W * xy2;
    };

    H10 P, C, N;
    hrow(i0 - 1, P);
    hrow(i0,     C);

    float acc = 0.0f;
#pragma unroll
    for (int rr = 0; rr < STRIP; ++rr) {
        hrow(min(i0 + rr + 1, IMG_W - 1), N);

        float racc = 0.0f;
#pragma unroll
        for (int k = 0; k < 2; ++k) {
            float s1  = A_W * (P.a1[k]  + N.a1[k])  + B_W * C.a1[k];
            float s2  = A_W * (P.a2[k]  + N.a2[k])  + B_W * C.a2[k];
            float s11 = A_W * (P.a11[k] + N.a11[k]) + B_W * C.a11[k];
            float s22 = A_W * (P.a22[k] + N.a22[k]) + B_W * C.a22[k];
            float s12 = A_W * (P.a12[k] + N.a12[k]) + B_W * C.a12[k];
            float v1 = s11 - s1 * s1;      // sigma1_sq
            float v2 = s22 - s2 * s2;      // sigma2_sq
            float cv = s12 - s1 * s2;      // sigma12
            racc += (k ? cm1 : cm0) * (v1 * v2 - 2.0f * cv);
        }
        acc += (i0 + rr < CROP_HI) ? racc : 0.0f;   // row mask (tail strip)
        P = C; C = N;
    }

    // Block reduction: 4 waves.
    for (int off = 32; off > 0; off >>= 1) acc += __shfl_down(acc, off, 64);
    __shared__ float wsum[BT / 64];
    if ((t & 63) == 0) wsum[t >> 6] = acc;
    __syncthreads();
    if (t == 0)
        partials[blockIdx.x + NSTRIPS * b] = wsum[0] + wsum[1] + wsum[2] + wsum[3];
}

__global__ __launch_bounds__(256) void ssim_loss_finalize(
    const float* __restrict__ partials, int n, float* __restrict__ out) {
    const int tid = threadIdx.x;
    float s = 0.0f;
    for (int i = tid; i < n; i += 256) s += partials[i];
    for (int off = 32; off > 0; off >>= 1) s += __shfl_down(s, off, 64);
    __shared__ float wsum[4];
    if ((tid & 63) == 0) wsum[tid >> 6] = s;
    __syncthreads();
    if (tid == 0) {
        float total = wsum[0] + wsum[1] + wsum[2] + wsum[3];
        out[0] = total * (1.0f / 252004.0f);   // mean over 502*502, summed over batch
    }
}

extern "C" void kernel_launch(void* const* d_in, const int* in_sizes, int n_in,
                              void* d_out, int out_size, void* d_ws, size_t ws_size,
                              hipStream_t stream) {
    const float* X = (const float*)d_in[0];
    const float* Y = (const float*)d_in[1];
    float* out = (float*)d_out;
    float* partials = (float*)d_ws;   // NSTRIPS*64 = 2048 floats

    dim3 grid(NSTRIPS, 64);
    ssim_loss_main<<<grid, BT, 0, stream>>>(X, Y, partials);
    ssim_loss_finalize<<<1, 256, 0, stream>>>(partials, NSTRIPS * 64, out);
}